// Round 6
// baseline (388.307 us; speedup 1.0000x reference)
//
#include <hip/hip_runtime.h>
#include <hip/hip_bf16.h>
#include <math.h>

typedef unsigned short u16;
typedef short s16x8 __attribute__((ext_vector_type(8)));
typedef float f32x4 __attribute__((ext_vector_type(4)));

// k-interleave within a 32-wide k-tile: lane group g reads contiguous 16B =
// k [4g..4g+3, 16+4g..16+4g+3]
__device__ __host__ __forceinline__ int KP(int k) {
    return ((k & 12) << 1) | (((k >> 4) & 1) << 2) | (k & 3);
}
// bank-conflict swizzle baked into the GLOBAL blocked layout (u16 index in tile).
// global_load_lds stages linearly; ds_read applies the same SWZ => consistent (rule #21).
__device__ __host__ __forceinline__ int SWZ(int row, int e) {
    return (row * 32 + e) ^ ((row & 15) << 3);
}

__device__ __forceinline__ float geluf(float x) {
    return 0.5f * x * (1.0f + erff(x * 0.70710678118654752f));
}
__device__ __forceinline__ u16 f2bf(float f) {
    unsigned u = __builtin_bit_cast(unsigned, f);
    return (u16)((u + 0x7fffu + ((u >> 16) & 1u)) >> 16);
}
__device__ __forceinline__ float bf2f(u16 h) {
    return __builtin_bit_cast(float, ((unsigned)h) << 16);
}
__device__ __forceinline__ void async_copy16(const u16* gsrc, u16* ldst) {
    __builtin_amdgcn_global_load_lds((const __attribute__((address_space(1))) void*)gsrc,
                                     (__attribute__((address_space(3))) void*)ldst, 16, 0, 0);
}
__device__ __forceinline__ float wave_reduce_sum(float v) {
    #pragma unroll
    for (int m = 32; m >= 1; m >>= 1) v += __shfl_xor(v, m, 64);
    return v;
}

#define MFMA(a, b, c) __builtin_amdgcn_mfma_f32_16x16x32_bf16(a, b, c, 0, 0, 0)
#define WAITVM(n) asm volatile("s_waitcnt vmcnt(" #n ")" ::: "memory")
#define RAW_BARRIER() __builtin_amdgcn_s_barrier()
#define SCHED_FENCE() __builtin_amdgcn_sched_barrier(0)

// ---------- prep: W[K][N] fp32 -> blocked bf16 tiles [(cb*K/32+kt)][CB rows][32], swizzled
__global__ __launch_bounds__(256) void prep_w(const float* __restrict__ W, u16* __restrict__ out,
                                              int K, int N, int CB) {
    int idx = blockIdx.x * 256 + threadIdx.x;
    if (idx >= K * N) return;
    int k = idx / N, col = idx % N;
    int cb = col / CB, ci = col % CB, kt = k >> 5, ki = k & 31;
    out[(size_t)(cb * (K >> 5) + kt) * (CB * 32) + SWZ(ci, KP(ki))] = f2bf(W[idx]);
}

// ---------- prep W1 feature rows (128..511) -> tiles [ks=f*4+dt][256 rows][32], swizzled
__global__ __launch_bounds__(256) void prep_w1(const float* __restrict__ W1, u16* __restrict__ out) {
    int idx = blockIdx.x * 256 + threadIdx.x;   // over 384*256
    if (idx >= 384 * 256) return;
    int k = idx / 256 + 128, col = idx % 256;
    int f = (k >> 7) - 1, dt = (k >> 5) & 3, ki = k & 31;
    out[(size_t)(f * 4 + dt) * 8192 + SWZ(col, KP(ki))] = f2bf(W1[(size_t)k * 256 + col]);
}

// ---------- nf = LN(ent + role_emb[roles]) -> blocked bf16 tiles [(row>>7)*24+kt][128][32], swizzled
__global__ __launch_bounds__(256) void nf_ln_kernel(
    const float* __restrict__ ent, const int* __restrict__ roles,
    const float* __restrict__ role_emb, const float* __restrict__ g,
    const float* __restrict__ bta, u16* __restrict__ nfb)
{
    int wave = threadIdx.x >> 6, lane = threadIdx.x & 63;
    int row = blockIdx.x * 4 + wave;
    const float* er = ent + (size_t)row * 768;
    const float* rr = role_emb + roles[row] * 768;
    float x[12]; float s = 0.f, s2 = 0.f;
    #pragma unroll
    for (int i = 0; i < 12; ++i) {
        x[i] = er[i * 64 + lane] + rr[i * 64 + lane];
        s += x[i]; s2 += x[i] * x[i];
    }
    s = wave_reduce_sum(s); s2 = wave_reduce_sum(s2);
    float mu = s * (1.f / 768.f);
    float var = s2 * (1.f / 768.f) - mu * mu;
    float rs = rsqrtf(var + 1e-5f);
    size_t rb = (size_t)(row >> 7) * 24;
    int rin = row & 127;
    #pragma unroll
    for (int i = 0; i < 12; ++i) {
        int k = i * 64 + lane;
        float v = (x[i] - mu) * rs * g[k] + bta[k];
        nfb[(rb + (k >> 5)) * 4096 + SWZ(rin, KP(k & 31))] = f2bf(v);
    }
}

// ---------- q = gelu(q_emb @ Wq + bq) -> bf16 [64][1024] row-major
__global__ __launch_bounds__(256) void q_kernel(
    const float* __restrict__ q_emb, const float* __restrict__ Wq,
    const float* __restrict__ bq, u16* __restrict__ qout)
{
    __shared__ float sq[768];
    int b = blockIdx.y;
    int col = blockIdx.x * 256 + threadIdx.x;
    for (int i = threadIdx.x; i < 768; i += 256) sq[i] = q_emb[b * 768 + i];
    __syncthreads();
    float acc = 0.f;
    #pragma unroll 4
    for (int k = 0; k < 768; ++k) acc = fmaf(sq[k], Wq[(size_t)k * 1024 + col], acc);
    qout[b * 1024 + col] = f2bf(geluf(acc + bq[col]));
}

// ---------- qw1[bh][col] = q[bh,:] @ W1[0:128, col] + b1[col]   (f32 [512][256])
__global__ __launch_bounds__(256) void qw1_kernel(
    const u16* __restrict__ qbuf, const float* __restrict__ W1,
    const float* __restrict__ b1, float* __restrict__ qw1)
{
    __shared__ float sq[128];
    int bh = blockIdx.x;
    int col = threadIdx.x;
    if (col < 128) sq[col] = bf2f(qbuf[bh * 128 + col]);
    __syncthreads();
    float acc = b1[col];
    #pragma unroll 4
    for (int d = 0; d < 128; ++d) acc = fmaf(sq[d], W1[d * 256 + col], acc);
    qw1[bh * 256 + col] = acc;
}

// ---------- kgemm3: k = gelu(nf @ Wk + bk); epilogue writes [k, |q-k|, q*k] blocked tiles
// rows' = b*1024 + h*128 + n ; kblk3 tiles [rt*12 + f*4 + dt][64][32] swizzled
// 3-stage pipeline, counted vmcnt, raw barriers. L=4 VMEM instr/wave/stage.
__global__ __launch_bounds__(256) void kgemm3(
    const u16* __restrict__ gA, const u16* __restrict__ gB,
    const float* __restrict__ bias, const u16* __restrict__ qbuf,
    u16* __restrict__ kblk3)
{
    __shared__ __attribute__((aligned(16))) u16 sm[24576];   // 48KB: A 3x4096 @0, B 3x4096 @12288
    const int tid = threadIdx.x, lane = tid & 63, w = tid >> 6;
    const int lr = lane & 15, g = lane >> 4;
    const int wr = w >> 1, wc = w & 1;
    const int nb = blockIdx.x, mb = blockIdx.y;   // h (0..7), b (0..63)
    const int NT = 24;
    f32x4 acc[4][4];
    #pragma unroll
    for (int i = 0; i < 4; ++i)
        #pragma unroll
        for (int j = 0; j < 4; ++j) acc[i][j] = (f32x4){0.f, 0.f, 0.f, 0.f};

    auto stage = [&](int t, int bi) {
        #pragma unroll
        for (int i = 0; i < 2; ++i) {
            int c = w * 2 + i;   // 0..7
            async_copy16(gA + (size_t)(mb * 24 + t) * 4096 + c * 512 + lane * 8, sm + bi * 4096 + c * 512);
            async_copy16(gB + (size_t)(nb * 24 + t) * 4096 + c * 512 + lane * 8, sm + 12288 + bi * 4096 + c * 512);
        }
    };
    stage(0, 0);
    stage(1, 1);
    for (int t = 0; t < NT; ++t) {
        int cur = t % 3;
        if (t + 2 < NT) { stage(t + 2, (t + 2) % 3); WAITVM(8); }
        else if (t + 1 < NT) WAITVM(4);
        else WAITVM(0);
        RAW_BARRIER();
        SCHED_FENCE();
        const u16* A = sm + cur * 4096;
        const u16* B = sm + 12288 + cur * 4096;
        s16x8 bfr[4];
        #pragma unroll
        for (int j = 0; j < 4; ++j) bfr[j] = *(const s16x8*)&B[SWZ(wc * 64 + j * 16 + lr, g * 8)];
        #pragma unroll
        for (int i = 0; i < 4; ++i) {
            s16x8 a = *(const s16x8*)&A[SWZ(wr * 64 + i * 16 + lr, g * 8)];
            #pragma unroll
            for (int j = 0; j < 4; ++j) acc[i][j] = MFMA(a, bfr[j], acc[i][j]);
        }
        SCHED_FENCE();
        RAW_BARRIER();
    }
    // epilogue: gelu(+bias); 3 feature passes via LDS-transpose; coalesced 16B stores
    float qv[4], bv[4];
    #pragma unroll
    for (int j = 0; j < 4; ++j) {
        int d = wc * 64 + j * 16 + lr;
        qv[j] = bf2f(qbuf[mb * 1024 + nb * 128 + d]);
        bv[j] = bias[nb * 128 + d];
    }
    #pragma unroll
    for (int i = 0; i < 4; ++i)
        #pragma unroll
        for (int j = 0; j < 4; ++j) {
            f32x4 t = acc[i][j];
            #pragma unroll
            for (int r = 0; r < 4; ++r) t[r] = geluf(t[r] + bv[j]);
            acc[i][j] = t;
        }
    for (int f = 0; f < 3; ++f) {
        #pragma unroll
        for (int i = 0; i < 4; ++i)
            #pragma unroll
            for (int j = 0; j < 4; ++j) {
                int d = wc * 64 + j * 16 + lr;
                #pragma unroll
                for (int r = 0; r < 4; ++r) {
                    int row = wr * 64 + i * 16 + 4 * g + r;
                    float kv = acc[i][j][r];
                    float v = (f == 0) ? kv : (f == 1) ? fabsf(qv[j] - kv) : qv[j] * kv;
                    sm[(wr * 4 + (d >> 5)) * 2048 + SWZ(row & 63, KP(d & 31))] = f2bf(v);
                }
            }
        __syncthreads();
        for (int u = tid; u < 2048; u += 256) {
            int tile_id = u >> 8, wrh = tile_id >> 2, dtt = tile_id & 3;
            int rt = mb * 16 + nb * 2 + wrh;
            *(f32x4*)&kblk3[((size_t)(rt * 12 + f * 4 + dtt)) * 2048 + (size_t)(u & 255) * 8] =
                *(const f32x4*)&sm[u * 8];
        }
        __syncthreads();
    }
}

// ---------- h1gemm: PURE streaming GEMM kblk3[rows' x 384] @ W1T[384 x 256]; +qW1 bias; gelu; LN -> h2A
// BM=64, BN=256, 256 thr (4 col-slice waves), acc[4][4], NT=12, 3-stage counted-vmcnt. L=5.
__global__ __launch_bounds__(256) void h1gemm(
    const u16* __restrict__ kblk3, const u16* __restrict__ w1t,
    const float* __restrict__ qw1, const float* __restrict__ g1v,
    const float* __restrict__ bb1, u16* __restrict__ h2A)
{
    __shared__ __attribute__((aligned(16))) u16 smA[6144];    // 3 x 2048 (4KB)
    __shared__ __attribute__((aligned(16))) u16 smB[24576];   // 3 x 8192 (16KB)
    __shared__ float part[64][4][2];
    const int tid = threadIdx.x, lane = tid & 63, w = tid >> 6;   // w = col slice 0..3
    const int lr = lane & 15, g = lane >> 4;
    const int mb = blockIdx.x;                 // 0..1023, rows' [mb*64, +64)
    const int NT = 12;
    f32x4 acc[4][4];
    #pragma unroll
    for (int i = 0; i < 4; ++i)
        #pragma unroll
        for (int j = 0; j < 4; ++j) acc[i][j] = (f32x4){0.f, 0.f, 0.f, 0.f};

    auto stage = [&](int t, int bi) {
        async_copy16(kblk3 + (size_t)(mb * 12 + t) * 2048 + w * 512 + lane * 8, smA + bi * 2048 + w * 512);
        #pragma unroll
        for (int i = 0; i < 4; ++i) {
            int c = w * 4 + i;   // 0..15
            async_copy16(w1t + (size_t)t * 8192 + c * 512 + lane * 8, smB + bi * 8192 + c * 512);
        }
    };
    stage(0, 0);
    stage(1, 1);
    for (int t = 0; t < NT; ++t) {
        int cur = t % 3;
        if (t + 2 < NT) { stage(t + 2, (t + 2) % 3); WAITVM(10); }
        else if (t + 1 < NT) WAITVM(5);
        else WAITVM(0);
        RAW_BARRIER();
        SCHED_FENCE();
        const u16* A = smA + cur * 2048;
        const u16* B = smB + cur * 8192;
        s16x8 bfr[4];
        #pragma unroll
        for (int j = 0; j < 4; ++j) bfr[j] = *(const s16x8*)&B[SWZ(w * 64 + j * 16 + lr, g * 8)];
        #pragma unroll
        for (int i = 0; i < 4; ++i) {
            s16x8 a = *(const s16x8*)&A[SWZ(i * 16 + lr, g * 8)];
            #pragma unroll
            for (int j = 0; j < 4; ++j) acc[i][j] = MFMA(a, bfr[j], acc[i][j]);
        }
        SCHED_FENCE();
        RAW_BARRIER();
    }
    // epilogue: + qW1 (q-block contribution incl. b1), gelu, LN over 256, swizzled blocked store
    const int bh = mb >> 1;
    float qb[4], g1c[4], b1c[4];
    #pragma unroll
    for (int j = 0; j < 4; ++j) {
        int col = w * 64 + j * 16 + lr;
        qb[j] = qw1[(size_t)bh * 256 + col];
        g1c[j] = g1v[col]; b1c[j] = bb1[col];
    }
    #pragma unroll
    for (int i = 0; i < 4; ++i)
        #pragma unroll
        for (int j = 0; j < 4; ++j) {
            f32x4 tt = acc[i][j];
            #pragma unroll
            for (int r = 0; r < 4; ++r) tt[r] = geluf(tt[r] + qb[j]);
            acc[i][j] = tt;
        }
    #pragma unroll
    for (int i = 0; i < 4; ++i)
        #pragma unroll
        for (int r = 0; r < 4; ++r) {
            float a = 0.f, bsq = 0.f;
            #pragma unroll
            for (int j = 0; j < 4; ++j) { float v = acc[i][j][r]; a += v; bsq += v * v; }
            #pragma unroll
            for (int m = 1; m <= 8; m <<= 1) { a += __shfl_xor(a, m, 64); bsq += __shfl_xor(bsq, m, 64); }
            if (lr == 0) {
                int r2 = i * 16 + 4 * g + r;
                part[r2][w][0] = a; part[r2][w][1] = bsq;
            }
        }
    __syncthreads();
    #pragma unroll
    for (int i = 0; i < 4; ++i)
        #pragma unroll
        for (int r = 0; r < 4; ++r) {
            int r2 = i * 16 + 4 * g + r;
            float S  = part[r2][0][0] + part[r2][1][0] + part[r2][2][0] + part[r2][3][0];
            float S2 = part[r2][0][1] + part[r2][1][1] + part[r2][2][1] + part[r2][3][1];
            float mu = S * (1.f / 256.f);
            float var = S2 * (1.f / 256.f) - mu * mu;
            float rs = rsqrtf(var + 1e-5f);
            int row_g = mb * 64 + r2;
            #pragma unroll
            for (int j = 0; j < 4; ++j) {
                int col = w * 64 + j * 16 + lr;
                float ln = (acc[i][j][r] - mu) * rs * g1c[j] + b1c[j];
                int rt2 = (row_g >> 7) * 8 + (col >> 5);
                h2A[(size_t)rt2 * 4096 + SWZ(row_g & 127, KP(col & 31))] = f2bf(ln);
            }
        }
}

// ---------- h2gemm: h2A[65536x256] @ W2[256x128]; gelu + LN + dot(W3) -> scores f32 [rows']
// 128x128 tile, NT=8, 3-stage counted-vmcnt. L=4.
__global__ __launch_bounds__(256) void h2gemm(
    const u16* __restrict__ h2A, const u16* __restrict__ w2t,
    const float* __restrict__ b2v, const float* __restrict__ g2v,
    const float* __restrict__ bb2, const float* __restrict__ W3,
    const float* __restrict__ b3, float* __restrict__ scores)
{
    __shared__ __attribute__((aligned(16))) u16 sm[24576];   // A 3x4096 @0, B 3x4096 @12288
    __shared__ float part[128][2][2];
    __shared__ float dotb[128][2];
    const int tid = threadIdx.x, lane = tid & 63, w = tid >> 6;
    const int lr = lane & 15, g = lane >> 4;
    const int wr = w >> 1, wc = w & 1;
    const int mb = blockIdx.x;   // 0..511
    const int NT = 8;
    f32x4 acc[4][4];
    #pragma unroll
    for (int i = 0; i < 4; ++i)
        #pragma unroll
        for (int j = 0; j < 4; ++j) acc[i][j] = (f32x4){0.f, 0.f, 0.f, 0.f};

    auto stage = [&](int t, int bi) {
        #pragma unroll
        for (int i = 0; i < 2; ++i) {
            int c = w * 2 + i;
            async_copy16(h2A + (size_t)(mb * 8 + t) * 4096 + c * 512 + lane * 8, sm + bi * 4096 + c * 512);
            async_copy16(w2t + (size_t)t * 4096 + c * 512 + lane * 8, sm + 12288 + bi * 4096 + c * 512);
        }
    };
    stage(0, 0);
    stage(1, 1);
    for (int t = 0; t < NT; ++t) {
        int cur = t % 3;
        if (t + 2 < NT) { stage(t + 2, (t + 2) % 3); WAITVM(8); }
        else if (t + 1 < NT) WAITVM(4);
        else WAITVM(0);
        RAW_BARRIER();
        SCHED_FENCE();
        const u16* A = sm + cur * 4096;
        const u16* B = sm + 12288 + cur * 4096;
        s16x8 bfr[4];
        #pragma unroll
        for (int j = 0; j < 4; ++j) bfr[j] = *(const s16x8*)&B[SWZ(wc * 64 + j * 16 + lr, g * 8)];
        #pragma unroll
        for (int i = 0; i < 4; ++i) {
            s16x8 a = *(const s16x8*)&A[SWZ(wr * 64 + i * 16 + lr, g * 8)];
            #pragma unroll
            for (int j = 0; j < 4; ++j) acc[i][j] = MFMA(a, bfr[j], acc[i][j]);
        }
        SCHED_FENCE();
        RAW_BARRIER();
    }
    float bkc[4], g2c[4], b2c[4], w3c[4];
    #pragma unroll
    for (int j = 0; j < 4; ++j) {
        int col = wc * 64 + j * 16 + lr;
        bkc[j] = b2v[col]; g2c[j] = g2v[col]; b2c[j] = bb2[col]; w3c[j] = W3[col];
    }
    #pragma unroll
    for (int i = 0; i < 4; ++i)
        #pragma unroll
        for (int j = 0; j < 4; ++j) {
            f32x4 tt = acc[i][j];
            #pragma unroll
            for (int r = 0; r < 4; ++r) tt[r] = geluf(tt[r] + bkc[j]);
            acc[i][j] = tt;
        }
    #pragma unroll
    for (int i = 0; i < 4; ++i)
        #pragma unroll
        for (int r = 0; r < 4; ++r) {
            float a = 0.f, bsq = 0.f;
            #pragma unroll
            for (int j = 0; j < 4; ++j) { float v = acc[i][j][r]; a += v; bsq += v * v; }
            #pragma unroll
            for (int m = 1; m <= 8; m <<= 1) { a += __shfl_xor(a, m, 64); bsq += __shfl_xor(bsq, m, 64); }
            if (lr == 0) {
                int rl = wr * 64 + i * 16 + 4 * g + r;
                part[rl][wc][0] = a; part[rl][wc][1] = bsq;
            }
        }
    __syncthreads();
    #pragma unroll
    for (int i = 0; i < 4; ++i)
        #pragma unroll
        for (int r = 0; r < 4; ++r) {
            int rl = wr * 64 + i * 16 + 4 * g + r;
            float S = part[rl][0][0] + part[rl][1][0];
            float S2 = part[rl][0][1] + part[rl][1][1];
            float mu = S * (1.f / 128.f);
            float var = S2 * (1.f / 128.f) - mu * mu;
            float rs = rsqrtf(var + 1e-5f);
            float d = 0.f;
            #pragma unroll
            for (int j = 0; j < 4; ++j) {
                float ln = (acc[i][j][r] - mu) * rs * g2c[j] + b2c[j];
                d += ln * w3c[j];
            }
            #pragma unroll
            for (int m = 1; m <= 8; m <<= 1) d += __shfl_xor(d, m, 64);
            if (lr == 0) dotb[rl][wc] = d;
        }
    __syncthreads();
    if (tid < 128) scores[(size_t)mb * 128 + tid] = dotb[tid][0] + dotb[tid][1] + b3[0];
}

// ---------- out[b] = sigmoid( sum_{h,n} score*gate*mask / 8 ), rows' = b*1024 + h*128 + n
__global__ __launch_bounds__(256) void final_kernel(
    const float* __restrict__ scores, const float* __restrict__ idfs,
    const float* __restrict__ mask, const float* __restrict__ gate_w,
    const float* __restrict__ gate_b, float* __restrict__ outp)
{
    int b = blockIdx.x, tid = threadIdx.x;
    float gw = gate_w[0], gb = gate_b[0];
    float acc = 0.f;
    for (int i = tid; i < 1024; i += 256) {
        int n = i & 127;
        float lg = log1pf(idfs[b * 128 + n]);
        float gate = 1.f / (1.f + expf(-(lg * gw + gb)));
        acc += scores[b * 1024 + i] * gate * mask[b * 128 + n];
    }
    acc = wave_reduce_sum(acc);
    __shared__ float wsum[4];
    if ((tid & 63) == 0) wsum[tid >> 6] = acc;
    __syncthreads();
    if (tid == 0) {
        float t = wsum[0] + wsum[1] + wsum[2] + wsum[3];
        outp[b] = 1.f / (1.f + expf(-t * 0.125f));
    }
}

extern "C" void kernel_launch(void* const* d_in, const int* in_sizes, int n_in,
                              void* d_out, int out_size, void* d_ws, size_t ws_size,
                              hipStream_t stream) {
    const float* q_emb    = (const float*)d_in[0];
    const float* ent      = (const float*)d_in[1];
    const int*   roles    = (const int*)d_in[2];
    const float* idfs     = (const float*)d_in[3];
    const float* mask     = (const float*)d_in[4];
    const float* role_emb = (const float*)d_in[5];
    const float* ln_f_g   = (const float*)d_in[6];
    const float* ln_f_b   = (const float*)d_in[7];
    const float* Wq       = (const float*)d_in[8];
    const float* bq       = (const float*)d_in[9];
    const float* Wk       = (const float*)d_in[10];
    const float* bk       = (const float*)d_in[11];
    const float* W1       = (const float*)d_in[12];
    const float* b1       = (const float*)d_in[13];
    const float* ln1_g    = (const float*)d_in[14];
    const float* ln1_b    = (const float*)d_in[15];
    const float* W2       = (const float*)d_in[16];
    const float* b2       = (const float*)d_in[17];
    const float* ln2_g    = (const float*)d_in[18];
    const float* ln2_b    = (const float*)d_in[19];
    const float* W3       = (const float*)d_in[20];
    const float* b3       = (const float*)d_in[21];
    const float* gate_w   = (const float*)d_in[22];
    const float* gate_b   = (const float*)d_in[23];
    float* outp = (float*)d_out;

    // workspace layout (bytes), disjoint; peak ~99.2 MB
    char* ws = (char*)d_ws;
    u16*   nfb    = (u16*)(ws);                          // 12,582,912
    u16*   kblk3  = (u16*)(ws + (size_t)12582912);       // 50,331,648
    u16*   h2A    = (u16*)(ws + (size_t)62914560);       // 33,554,432
    u16*   WkT    = (u16*)(ws + (size_t)96468992);       //  1,572,864
    u16*   W1T    = (u16*)(ws + (size_t)98041856);       //    196,608
    u16*   W2T    = (u16*)(ws + (size_t)98238464);       //     65,536
    u16*   qbuf   = (u16*)(ws + (size_t)98304000);       //    131,072
    float* qw1    = (float*)(ws + (size_t)98435072);     //    524,288
    float* scores = (float*)(ws + (size_t)98959360);     //    262,144

    prep_w<<<3072, 256, 0, stream>>>(Wk, WkT, 768, 1024, 128);
    prep_w<<<128, 256, 0, stream>>>(W2, W2T, 256, 128, 128);
    prep_w1<<<384, 256, 0, stream>>>(W1, W1T);
    nf_ln_kernel<<<2048, 256, 0, stream>>>(ent, roles, role_emb, ln_f_g, ln_f_b, nfb);
    q_kernel<<<dim3(4, 64), 256, 0, stream>>>(q_emb, Wq, bq, qbuf);
    qw1_kernel<<<512, 256, 0, stream>>>(qbuf, W1, b1, qw1);
    kgemm3<<<dim3(8, 64), 256, 0, stream>>>(nfb, WkT, bk, qbuf, kblk3);
    h1gemm<<<1024, 256, 0, stream>>>(kblk3, W1T, qw1, ln1_g, ln1_b, h2A);
    h2gemm<<<512, 256, 0, stream>>>(h2A, W2T, b2, ln2_g, ln2_b, W3, b3, scores);
    final_kernel<<<64, 256, 0, stream>>>(scores, idfs, mask, gate_w, gate_b, outp);
}

// Round 7
// 310.658 us; speedup vs baseline: 1.2500x; 1.2500x over previous
//
#include <hip/hip_runtime.h>
#include <hip/hip_bf16.h>
#include <math.h>

typedef unsigned short u16;
typedef short s16x8 __attribute__((ext_vector_type(8)));
typedef float f32x4 __attribute__((ext_vector_type(4)));
typedef unsigned u32x4 __attribute__((ext_vector_type(4)));

// k-interleave within a 32-wide k-tile: lane group g reads contiguous 16B =
// k [4g..4g+3, 16+4g..16+4g+3]
__device__ __host__ __forceinline__ int KP(int k) {
    return ((k & 12) << 1) | (((k >> 4) & 1) << 2) | (k & 3);
}
// bank-conflict swizzle baked into GLOBAL blocked layouts staged via global_load_lds
__device__ __host__ __forceinline__ int SWZ(int row, int e) {
    return (row * 32 + e) ^ ((row & 15) << 3);
}

__device__ __forceinline__ float geluf(float x) {
    return 0.5f * x * (1.0f + erff(x * 0.70710678118654752f));
}
__device__ __forceinline__ u16 f2bf(float f) {
    unsigned u = __builtin_bit_cast(unsigned, f);
    return (u16)((u + 0x7fffu + ((u >> 16) & 1u)) >> 16);
}
__device__ __forceinline__ float bf2f(u16 h) {
    return __builtin_bit_cast(float, ((unsigned)h) << 16);
}
__device__ __forceinline__ void async_copy16(const u16* gsrc, u16* ldst) {
    __builtin_amdgcn_global_load_lds((const __attribute__((address_space(1))) void*)gsrc,
                                     (__attribute__((address_space(3))) void*)ldst, 16, 0, 0);
}
__device__ __forceinline__ float wave_reduce_sum(float v) {
    #pragma unroll
    for (int m = 32; m >= 1; m >>= 1) v += __shfl_xor(v, m, 64);
    return v;
}

// packed-bf16 |q-k| and q*k (truncating round; proven in R3)
__device__ __forceinline__ s16x8 feat_abs(s16x8 k, s16x8 q) {
    u32x4 kk = __builtin_bit_cast(u32x4, k), qq = __builtin_bit_cast(u32x4, q);
    u32x4 o;
    #pragma unroll
    for (int p = 0; p < 4; ++p) {
        unsigned kp = kk[p], qp = qq[p];
        float klo = __builtin_bit_cast(float, kp << 16);
        float khi = __builtin_bit_cast(float, kp & 0xFFFF0000u);
        float qlo = __builtin_bit_cast(float, qp << 16);
        float qhi = __builtin_bit_cast(float, qp & 0xFFFF0000u);
        unsigned dlo = __builtin_bit_cast(unsigned, qlo - klo) & 0x7FFFFFFFu;
        unsigned dhi = __builtin_bit_cast(unsigned, qhi - khi) & 0x7FFFFFFFu;
        o[p] = (dhi & 0xFFFF0000u) | (dlo >> 16);
    }
    return __builtin_bit_cast(s16x8, o);
}
__device__ __forceinline__ s16x8 feat_mul(s16x8 k, s16x8 q) {
    u32x4 kk = __builtin_bit_cast(u32x4, k), qq = __builtin_bit_cast(u32x4, q);
    u32x4 o;
    #pragma unroll
    for (int p = 0; p < 4; ++p) {
        unsigned kp = kk[p], qp = qq[p];
        float klo = __builtin_bit_cast(float, kp << 16);
        float khi = __builtin_bit_cast(float, kp & 0xFFFF0000u);
        float qlo = __builtin_bit_cast(float, qp << 16);
        float qhi = __builtin_bit_cast(float, qp & 0xFFFF0000u);
        unsigned plo = __builtin_bit_cast(unsigned, qlo * klo);
        unsigned phi = __builtin_bit_cast(unsigned, qhi * khi);
        o[p] = (phi & 0xFFFF0000u) | (plo >> 16);
    }
    return __builtin_bit_cast(s16x8, o);
}

#define MFMA(a, b, c) __builtin_amdgcn_mfma_f32_16x16x32_bf16(a, b, c, 0, 0, 0)

// ---------- prep: W[K][N] fp32 -> blocked bf16 tiles [(cb*K/32+kt)][CB rows][32], SWZ (for glds staging)
__global__ __launch_bounds__(256) void prep_w(const float* __restrict__ W, u16* __restrict__ out,
                                              int K, int N, int CB) {
    int idx = blockIdx.x * 256 + threadIdx.x;
    if (idx >= K * N) return;
    int k = idx / N, col = idx % N;
    int cb = col / CB, ci = col % CB, kt = k >> 5, ki = k & 31;
    out[(size_t)(cb * (K >> 5) + kt) * (CB * 32) + SWZ(ci, KP(ki))] = f2bf(W[idx]);
}

// ---------- prep W1 rows 128..511 -> [ks=f*4+dt][256 cols][32] PLAIN KP (read per-lane to regs)
__global__ __launch_bounds__(256) void prep_w1(const float* __restrict__ W1, u16* __restrict__ out) {
    int idx = blockIdx.x * 256 + threadIdx.x;   // 384*256
    if (idx >= 384 * 256) return;
    int k = idx / 256 + 128, col = idx % 256;
    int f = (k >> 7) - 1, dt = (k >> 5) & 3, ki = k & 31;
    out[(size_t)(f * 4 + dt) * 8192 + col * 32 + KP(ki)] = f2bf(W1[(size_t)k * 256 + col]);
}

// ---------- prep W2' = g1 scaled rows -> [ks][128 cols][32] PLAIN KP
__global__ __launch_bounds__(256) void prep_w2k(const float* __restrict__ W2,
                                                const float* __restrict__ g1, u16* __restrict__ w2t) {
    int idx = blockIdx.x * 256 + threadIdx.x;   // 256*128
    if (idx >= 32768) return;
    int k = idx >> 7, c = idx & 127;
    w2t[(size_t)(k >> 5) * 4096 + c * 32 + KP(k & 31)] = f2bf(g1[k] * W2[(size_t)k * 128 + c]);
}
// bias2[c] = b2[c] + sum_k ln1_b[k] * W2[k,c]
__global__ void prep_bias2(const float* __restrict__ W2, const float* __restrict__ b1v,
                           const float* __restrict__ b2, float* __restrict__ bias2) {
    int c = threadIdx.x;   // 128
    float s = b2[c];
    for (int k = 0; k < 256; ++k) s += b1v[k] * W2[k * 128 + c];
    bias2[c] = s;
}

// ---------- nf = LN(ent + role_emb[roles]) -> blocked bf16 tiles [(b)*24+kt][128][32], SWZ
__global__ __launch_bounds__(256) void nf_ln_kernel(
    const float* __restrict__ ent, const int* __restrict__ roles,
    const float* __restrict__ role_emb, const float* __restrict__ g,
    const float* __restrict__ bta, u16* __restrict__ nfb)
{
    int wave = threadIdx.x >> 6, lane = threadIdx.x & 63;
    int row = blockIdx.x * 4 + wave;
    const float* er = ent + (size_t)row * 768;
    const float* rr = role_emb + roles[row] * 768;
    float x[12]; float s = 0.f, s2 = 0.f;
    #pragma unroll
    for (int i = 0; i < 12; ++i) {
        x[i] = er[i * 64 + lane] + rr[i * 64 + lane];
        s += x[i]; s2 += x[i] * x[i];
    }
    s = wave_reduce_sum(s); s2 = wave_reduce_sum(s2);
    float mu = s * (1.f / 768.f);
    float var = s2 * (1.f / 768.f) - mu * mu;
    float rs = rsqrtf(var + 1e-5f);
    size_t rb = (size_t)(row >> 7) * 24;
    int rin = row & 127;
    #pragma unroll
    for (int i = 0; i < 12; ++i) {
        int k = i * 64 + lane;
        float v = (x[i] - mu) * rs * g[k] + bta[k];
        nfb[(rb + (k >> 5)) * 4096 + SWZ(rin, KP(k & 31))] = f2bf(v);
    }
}

// ---------- q = gelu(q_emb @ Wq + bq) -> bf16 [64][1024]
__global__ __launch_bounds__(256) void q_kernel(
    const float* __restrict__ q_emb, const float* __restrict__ Wq,
    const float* __restrict__ bq, u16* __restrict__ qout)
{
    __shared__ float sq[768];
    int b = blockIdx.y;
    int col = blockIdx.x * 256 + threadIdx.x;
    for (int i = threadIdx.x; i < 768; i += 256) sq[i] = q_emb[b * 768 + i];
    __syncthreads();
    float acc = 0.f;
    #pragma unroll 4
    for (int k = 0; k < 768; ++k) acc = fmaf(sq[k], Wq[(size_t)k * 1024 + col], acc);
    qout[b * 1024 + col] = f2bf(geluf(acc + bq[col]));
}

// ---------- qw1[bh][col] = q[bh,:] @ W1[0:128, col] + b1[col]
__global__ __launch_bounds__(256) void qw1_kernel(
    const u16* __restrict__ qbuf, const float* __restrict__ W1,
    const float* __restrict__ b1, float* __restrict__ qw1)
{
    __shared__ float sq[128];
    int bh = blockIdx.x;
    int col = threadIdx.x;
    if (col < 128) sq[col] = bf2f(qbuf[bh * 128 + col]);
    __syncthreads();
    float acc = b1[col];
    #pragma unroll 4
    for (int d = 0; d < 128; ++d) acc = fmaf(sq[d], W1[d * 256 + col], acc);
    qw1[bh * 256 + col] = acc;
}

// ============ MEGA: one block per (b,h): k-GEMM -> features -> h1 -> h2 -> scores ============
// LDS map (u16 units):
//   [0,16384)      ph1 staging  As 2x4096 | Bs 2x4096 @8192   ; later A2 chunks dt3 0..3
//   [16384,33792)  ktile [128][136] KP-chunked                ; later A2 chunks dt3 4..7
//   [33792,35840)  part [128][4][2] f32 ; ph3-epilogue part2/dotb
__global__ __launch_bounds__(256, 2) void mega(
    const u16* __restrict__ nfb, const u16* __restrict__ wkt,
    const float* __restrict__ bk, const u16* __restrict__ qbuf,
    const u16* __restrict__ w1t, const float* __restrict__ qw1,
    const u16* __restrict__ w2t, const float* __restrict__ bias2,
    const float* __restrict__ g2v, const float* __restrict__ bb2,
    const float* __restrict__ W3, const float* __restrict__ b3,
    float* __restrict__ scores)
{
    __shared__ __attribute__((aligned(16))) u16 sm[35840];
    const int tid = threadIdx.x, lane = tid & 63, w = tid >> 6;
    const int lr = lane & 15, g = lane >> 4;
    const int wr = w >> 1, wc = w & 1;
    const int bid = blockIdx.x;
    const int b = bid & 63, h = bid >> 6;   // bid%8 = b%8 -> same-b-class per XCD

    f32x4 acc[4][4];
    #pragma unroll
    for (int i = 0; i < 4; ++i)
        #pragma unroll
        for (int j = 0; j < 4; ++j) acc[i][j] = (f32x4){0.f, 0.f, 0.f, 0.f};

    // ---------------- phase 1: ktile = gelu(nf[b] @ Wk[:, h*128..+128) + bk), K=768
    auto stage1 = [&](int t, int bi) {
        #pragma unroll
        for (int i2 = 0; i2 < 2; ++i2) {
            int c = w * 2 + i2;
            async_copy16(nfb + (size_t)(b * 24 + t) * 4096 + c * 512 + lane * 8, sm + bi * 4096 + c * 512);
            async_copy16(wkt + (size_t)(h * 24 + t) * 4096 + c * 512 + lane * 8, sm + 8192 + bi * 4096 + c * 512);
        }
    };
    stage1(0, 0);
    __syncthreads();
    for (int t = 0; t < 24; ++t) {
        int cur = t & 1;
        if (t + 1 < 24) stage1(t + 1, cur ^ 1);
        const u16* A = sm + cur * 4096;
        const u16* B = sm + 8192 + cur * 4096;
        s16x8 bfr[4];
        #pragma unroll
        for (int j = 0; j < 4; ++j) bfr[j] = *(const s16x8*)&B[SWZ(wc * 64 + j * 16 + lr, g * 8)];
        #pragma unroll
        for (int i = 0; i < 4; ++i) {
            s16x8 a = *(const s16x8*)&A[SWZ(wr * 64 + i * 16 + lr, g * 8)];
            #pragma unroll
            for (int j = 0; j < 4; ++j) acc[i][j] = MFMA(a, bfr[j], acc[i][j]);
        }
        __syncthreads();
    }
    // ph1 epilogue -> ktile bf16 [128][136], d-chunks KP'd
    {
        u16* ktile = sm + 16384;
        float bkc[4];
        #pragma unroll
        for (int j = 0; j < 4; ++j) bkc[j] = bk[h * 128 + wc * 64 + j * 16 + lr];
        #pragma unroll
        for (int i = 0; i < 4; ++i)
            #pragma unroll
            for (int j = 0; j < 4; ++j) {
                int chunk = wc * 2 + (j >> 1);
                int pos = ((lr & 12) << 1) | ((j & 1) << 2) | (lr & 3);
                #pragma unroll
                for (int r = 0; r < 4; ++r) {
                    int row = wr * 64 + i * 16 + 4 * g + r;
                    ktile[row * 136 + chunk * 32 + pos] = f2bf(geluf(acc[i][j][r] + bkc[j]));
                }
            }
    }
    __syncthreads();

    // q fragments (packed bf16 pairs matching kfrag layout)
    s16x8 qf[4];
    {
        const u16* qp = qbuf + b * 1024 + h * 128;
        #pragma unroll
        for (int dt = 0; dt < 4; ++dt) {
            uint2 lo = *(const uint2*)&qp[dt * 32 + 4 * g];
            uint2 hi = *(const uint2*)&qp[dt * 32 + 16 + 4 * g];
            u32x4 tmp = (u32x4){lo.x, lo.y, hi.x, hi.y};
            qf[dt] = __builtin_bit_cast(s16x8, tmp);
        }
    }
    float qwc[2][4];
    #pragma unroll
    for (int H = 0; H < 2; ++H)
        #pragma unroll
        for (int j = 0; j < 4; ++j)
            qwc[H][j] = qw1[(size_t)(b * 8 + h) * 256 + H * 128 + wc * 64 + j * 16 + lr];

    float* part = (float*)(sm + 33792);   // [128][4 slots][2]
    const u16* ktile = sm + 16384;

    // ---------------- phase 2: h1 halves (cols H*128..+128), K=384, barrier-free loop
    #pragma unroll 1
    for (int H = 0; H < 2; ++H) {
        #pragma unroll
        for (int i = 0; i < 4; ++i)
            #pragma unroll
            for (int j = 0; j < 4; ++j) acc[i][j] = (f32x4){0.f, 0.f, 0.f, 0.f};
        s16x8 bnx[4];
        {
            const u16* bb = w1t + (size_t)0 * 8192 + (H * 128 + wc * 64 + lr) * 32 + g * 8;
            #pragma unroll
            for (int j = 0; j < 4; ++j) bnx[j] = *(const s16x8*)(bb + j * 512);
        }
        #pragma unroll
        for (int st = 0; st < 12; ++st) {
            int f = st >> 2, dt = st & 3;
            s16x8 bcur[4];
            #pragma unroll
            for (int j = 0; j < 4; ++j) bcur[j] = bnx[j];
            if (st < 11) {
                int ks = st + 1;
                const u16* bb = w1t + (size_t)ks * 8192 + (H * 128 + wc * 64 + lr) * 32 + g * 8;
                #pragma unroll
                for (int j = 0; j < 4; ++j) bnx[j] = *(const s16x8*)(bb + j * 512);
            }
            #pragma unroll
            for (int i = 0; i < 4; ++i) {
                s16x8 kf = *(const s16x8*)&ktile[(wr * 64 + i * 16 + lr) * 136 + dt * 32 + g * 8];
                s16x8 af = (f == 0) ? kf : (f == 1) ? feat_abs(kf, qf[dt]) : feat_mul(kf, qf[dt]);
                #pragma unroll
                for (int j = 0; j < 4; ++j) acc[i][j] = MFMA(af, bcur[j], acc[i][j]);
            }
        }
        if (H == 1) __syncthreads();   // all ktile reads done before A2H1 overwrites it
        // half epilogue: gelu(+qw1), row sums -> part, pre-LN bf16 -> A2
        #pragma unroll
        for (int i = 0; i < 4; ++i)
            #pragma unroll
            for (int j = 0; j < 4; ++j) {
                f32x4 t = acc[i][j];
                #pragma unroll
                for (int r = 0; r < 4; ++r) t[r] = geluf(t[r] + qwc[H][j]);
                acc[i][j] = t;
            }
        #pragma unroll
        for (int i = 0; i < 4; ++i)
            #pragma unroll
            for (int r = 0; r < 4; ++r) {
                float s = 0.f, s2 = 0.f;
                #pragma unroll
                for (int j = 0; j < 4; ++j) { float v = acc[i][j][r]; s += v; s2 += v * v; }
                #pragma unroll
                for (int m = 1; m <= 8; m <<= 1) { s += __shfl_xor(s, m, 64); s2 += __shfl_xor(s2, m, 64); }
                if (lr == 0) {
                    int row = wr * 64 + i * 16 + 4 * g + r;
                    int slot = H * 2 + wc;
                    part[(row * 4 + slot) * 2 + 0] = s;
                    part[(row * 4 + slot) * 2 + 1] = s2;
                }
            }
        #pragma unroll
        for (int i = 0; i < 4; ++i)
            #pragma unroll
            for (int j = 0; j < 4; ++j) {
                int dt3 = H * 4 + wc * 2 + (j >> 1);
                int e = ((lr & 12) << 1) | ((j & 1) << 2) | (lr & 3);
                int base = (dt3 < 4) ? dt3 * 4096 : 16384 + (dt3 - 4) * 4096;
                #pragma unroll
                for (int r = 0; r < 4; ++r) {
                    int row = wr * 64 + i * 16 + 4 * g + r;
                    sm[base + row * 32 + (e ^ ((row & 3) << 3))] = f2bf(acc[i][j][r]);
                }
            }
    }
    __syncthreads();

    // LN constants for my ph3 fragment rows
    float c0[4], c1[4];
    #pragma unroll
    for (int i = 0; i < 4; ++i) {
        int row = wr * 64 + i * 16 + lr;
        float S = part[row * 8 + 0] + part[row * 8 + 2] + part[row * 8 + 4] + part[row * 8 + 6];
        float S2 = part[row * 8 + 1] + part[row * 8 + 3] + part[row * 8 + 5] + part[row * 8 + 7];
        float mu = S * (1.f / 256.f);
        float var = S2 * (1.f / 256.f) - mu * mu;
        float rs = rsqrtf(var + 1e-5f);
        c1[i] = rs; c0[i] = -mu * rs;
    }

    // ---------------- phase 3: h2 = y @ W2' + bias2, K=256, barrier-free
    f32x4 acc2[4][4];
    #pragma unroll
    for (int i = 0; i < 4; ++i)
        #pragma unroll
        for (int j = 0; j < 4; ++j) acc2[i][j] = (f32x4){0.f, 0.f, 0.f, 0.f};
    s16x8 b2n[4];
    {
        const u16* bb = w2t + (size_t)0 * 4096 + (wc * 64 + lr) * 32 + g * 8;
        #pragma unroll
        for (int j = 0; j < 4; ++j) b2n[j] = *(const s16x8*)(bb + j * 512);
    }
    #pragma unroll
    for (int ks = 0; ks < 8; ++ks) {
        s16x8 b2c[4];
        #pragma unroll
        for (int j = 0; j < 4; ++j) b2c[j] = b2n[j];
        if (ks < 7) {
            const u16* bb = w2t + (size_t)(ks + 1) * 4096 + (wc * 64 + lr) * 32 + g * 8;
            #pragma unroll
            for (int j = 0; j < 4; ++j) b2n[j] = *(const s16x8*)(bb + j * 512);
        }
        int base = (ks < 4) ? ks * 4096 : 16384 + (ks - 4) * 4096;
        #pragma unroll
        for (int i = 0; i < 4; ++i) {
            int row = wr * 64 + i * 16 + lr;
            int e0 = (g * 8) ^ ((row & 3) << 3);
            u32x4 raw = *(const u32x4*)&sm[base + row * 32 + e0];
            u32x4 outv;
            #pragma unroll
            for (int p = 0; p < 4; ++p) {
                float lo = __builtin_bit_cast(float, raw[p] << 16);
                float hi = __builtin_bit_cast(float, raw[p] & 0xFFFF0000u);
                float ylo = fmaf(lo, c1[i], c0[i]);
                float yhi = fmaf(hi, c1[i], c0[i]);
                outv[p] = (__builtin_bit_cast(unsigned, yhi) & 0xFFFF0000u) |
                          (__builtin_bit_cast(unsigned, ylo) >> 16);
            }
            s16x8 af = __builtin_bit_cast(s16x8, outv);
            #pragma unroll
            for (int j = 0; j < 4; ++j) acc2[i][j] = MFMA(af, b2c[j], acc2[i][j]);
        }
    }
    // ---------------- epilogue: +bias2, gelu, LN(128) with g2/b2, dot W3 -> scores
    __syncthreads();
    float* part2 = (float*)(sm + 33792);          // [128][2][2]
    float* dotb  = (float*)(sm + 33792 + 1024);   // [128][2]
    float bc2[4], g2c[4], b2cv[4], w3c[4];
    #pragma unroll
    for (int j = 0; j < 4; ++j) {
        int col = wc * 64 + j * 16 + lr;
        bc2[j] = bias2[col]; g2c[j] = g2v[col]; b2cv[j] = bb2[col]; w3c[j] = W3[col];
    }
    #pragma unroll
    for (int i = 0; i < 4; ++i)
        #pragma unroll
        for (int j = 0; j < 4; ++j) {
            f32x4 t = acc2[i][j];
            #pragma unroll
            for (int r = 0; r < 4; ++r) t[r] = geluf(t[r] + bc2[j]);
            acc2[i][j] = t;
        }
    #pragma unroll
    for (int i = 0; i < 4; ++i)
        #pragma unroll
        for (int r = 0; r < 4; ++r) {
            float s = 0.f, s2 = 0.f;
            #pragma unroll
            for (int j = 0; j < 4; ++j) { float v = acc2[i][j][r]; s += v; s2 += v * v; }
            #pragma unroll
            for (int m = 1; m <= 8; m <<= 1) { s += __shfl_xor(s, m, 64); s2 += __shfl_xor(s2, m, 64); }
            if (lr == 0) {
                int rl = wr * 64 + i * 16 + 4 * g + r;
                part2[(rl * 2 + wc) * 2 + 0] = s;
                part2[(rl * 2 + wc) * 2 + 1] = s2;
            }
        }
    __syncthreads();
    #pragma unroll
    for (int i = 0; i < 4; ++i)
        #pragma unroll
        for (int r = 0; r < 4; ++r) {
            int rl = wr * 64 + i * 16 + 4 * g + r;
            float S = part2[rl * 4 + 0] + part2[rl * 4 + 2];
            float S2 = part2[rl * 4 + 1] + part2[rl * 4 + 3];
            float mu = S * (1.f / 128.f);
            float var = S2 * (1.f / 128.f) - mu * mu;
            float rs = rsqrtf(var + 1e-5f);
            float d = 0.f;
            #pragma unroll
            for (int j = 0; j < 4; ++j) {
                float ln = (acc2[i][j][r] - mu) * rs * g2c[j] + b2cv[j];
                d += ln * w3c[j];
            }
            #pragma unroll
            for (int m = 1; m <= 8; m <<= 1) d += __shfl_xor(d, m, 64);
            if (lr == 0) dotb[rl * 2 + wc] = d;
        }
    __syncthreads();
    if (tid < 128)
        scores[(size_t)(b * 8 + h) * 128 + tid] = dotb[tid * 2] + dotb[tid * 2 + 1] + b3[0];
}

// ---------- out[b] = sigmoid( sum_{h,n} score*gate*mask / 8 ), scores [b][h][n]
__global__ __launch_bounds__(256) void final_kernel(
    const float* __restrict__ scores, const float* __restrict__ idfs,
    const float* __restrict__ mask, const float* __restrict__ gate_w,
    const float* __restrict__ gate_b, float* __restrict__ outp)
{
    int b = blockIdx.x, tid = threadIdx.x;
    float gw = gate_w[0], gb = gate_b[0];
    float acc = 0.f;
    for (int i = tid; i < 1024; i += 256) {
        int n = i & 127;
        float lg = log1pf(idfs[b * 128 + n]);
        float gate = 1.f / (1.f + expf(-(lg * gw + gb)));
        acc += scores[b * 1024 + i] * gate * mask[b * 128 + n];
    }
    acc = wave_reduce_sum(acc);
    __shared__ float wsum[4];
    if ((tid & 63) == 0) wsum[tid >> 6] = acc;
    __syncthreads();
    if (tid == 0) {
        float t = wsum[0] + wsum[1] + wsum[2] + wsum[3];
        outp[b] = 1.f / (1.f + expf(-t * 0.125f));
    }
}

extern "C" void kernel_launch(void* const* d_in, const int* in_sizes, int n_in,
                              void* d_out, int out_size, void* d_ws, size_t ws_size,
                              hipStream_t stream) {
    const float* q_emb    = (const float*)d_in[0];
    const float* ent      = (const float*)d_in[1];
    const int*   roles    = (const int*)d_in[2];
    const float* idfs     = (const float*)d_in[3];
    const float* mask     = (const float*)d_in[4];
    const float* role_emb = (const float*)d_in[5];
    const float* ln_f_g   = (const float*)d_in[6];
    const float* ln_f_b   = (const float*)d_in[7];
    const float* Wq       = (const float*)d_in[8];
    const float* bq       = (const float*)d_in[9];
    const float* Wk       = (const float*)d_in[10];
    const float* bk       = (const float*)d_in[11];
    const float* W1       = (const float*)d_in[12];
    const float* b1       = (const float*)d_in[13];
    const float* ln1_g    = (const float*)d_in[14];
    const float* ln1_b    = (const float*)d_in[15];
    const float* W2       = (const float*)d_in[16];
    const float* b2       = (const float*)d_in[17];
    const float* ln2_g    = (const float*)d_in[18];
    const float* ln2_b    = (const float*)d_in[19];
    const float* W3       = (const float*)d_in[20];
    const float* b3       = (const float*)d_in[21];
    const float* gate_w   = (const float*)d_in[22];
    const float* gate_b   = (const float*)d_in[23];
    float* outp = (float*)d_out;

    // workspace layout (bytes), disjoint; peak ~15.4 MB
    char* ws = (char*)d_ws;
    u16*   nfb    = (u16*)(ws);                          // 12,582,912
    u16*   WkT    = (u16*)(ws + (size_t)12582912);       //  1,572,864
    u16*   W1T    = (u16*)(ws + (size_t)14155776);       //    196,608
    u16*   W2T    = (u16*)(ws + (size_t)14352384);       //     65,536
    u16*   qbuf   = (u16*)(ws + (size_t)14417920);       //    131,072
    float* qw1    = (float*)(ws + (size_t)14548992);     //    524,288
    float* bias2  = (float*)(ws + (size_t)15073280);     //        512
    float* scores = (float*)(ws + (size_t)15073792);     //    262,144

    prep_w<<<3072, 256, 0, stream>>>(Wk, WkT, 768, 1024, 128);
    prep_w1<<<384, 256, 0, stream>>>(W1, W1T);
    prep_w2k<<<128, 256, 0, stream>>>(W2, ln1_g, W2T);
    prep_bias2<<<1, 128, 0, stream>>>(W2, ln1_b, b2, bias2);
    nf_ln_kernel<<<2048, 256, 0, stream>>>(ent, roles, role_emb, ln_f_g, ln_f_b, nfb);
    q_kernel<<<dim3(4, 64), 256, 0, stream>>>(q_emb, Wq, bq, qbuf);
    qw1_kernel<<<512, 256, 0, stream>>>(qbuf, W1, b1, qw1);
    mega<<<512, 256, 0, stream>>>(nfb, WkT, bk, qbuf, W1T, qw1, W2T, bias2,
                                  ln2_g, ln2_b, W3, b3, scores);
    final_kernel<<<64, 256, 0, stream>>>(scores, idfs, mask, gate_w, gate_b, outp);
}

// Round 8
// 260.582 us; speedup vs baseline: 1.4901x; 1.1922x over previous
//
#include <hip/hip_runtime.h>
#include <hip/hip_bf16.h>
#include <math.h>

typedef unsigned short u16;
typedef short s16x8 __attribute__((ext_vector_type(8)));
typedef float f32x4 __attribute__((ext_vector_type(4)));
typedef unsigned u32x4 __attribute__((ext_vector_type(4)));

// k-interleave within a 32-wide k-tile: lane group g reads contiguous 16B =
// k [4g..4g+3, 16+4g..16+4g+3]
__device__ __host__ __forceinline__ int KP(int k) {
    return ((k & 12) << 1) | (((k >> 4) & 1) << 2) | (k & 3);
}

__device__ __forceinline__ float geluf(float x) {
    return 0.5f * x * (1.0f + erff(x * 0.70710678118654752f));
}
__device__ __forceinline__ u16 f2bf(float f) {
    unsigned u = __builtin_bit_cast(unsigned, f);
    return (u16)((u + 0x7fffu + ((u >> 16) & 1u)) >> 16);
}
__device__ __forceinline__ float bf2f(u16 h) {
    return __builtin_bit_cast(float, ((unsigned)h) << 16);
}
__device__ __forceinline__ void async_copy16(const u16* gsrc, u16* ldst) {
    __builtin_amdgcn_global_load_lds((const __attribute__((address_space(1))) void*)gsrc,
                                     (__attribute__((address_space(3))) void*)ldst, 16, 0, 0);
}
__device__ __forceinline__ float wave_reduce_sum(float v) {
    #pragma unroll
    for (int m = 32; m >= 1; m >>= 1) v += __shfl_xor(v, m, 64);
    return v;
}

// packed-bf16 |q-k| and q*k (proven R3)
__device__ __forceinline__ s16x8 feat_abs(s16x8 k, s16x8 q) {
    u32x4 kk = __builtin_bit_cast(u32x4, k), qq = __builtin_bit_cast(u32x4, q);
    u32x4 o;
    #pragma unroll
    for (int p = 0; p < 4; ++p) {
        unsigned kp = kk[p], qp = qq[p];
        float klo = __builtin_bit_cast(float, kp << 16);
        float khi = __builtin_bit_cast(float, kp & 0xFFFF0000u);
        float qlo = __builtin_bit_cast(float, qp << 16);
        float qhi = __builtin_bit_cast(float, qp & 0xFFFF0000u);
        unsigned dlo = __builtin_bit_cast(unsigned, qlo - klo) & 0x7FFFFFFFu;
        unsigned dhi = __builtin_bit_cast(unsigned, qhi - khi) & 0x7FFFFFFFu;
        o[p] = (dhi & 0xFFFF0000u) | (dlo >> 16);
    }
    return __builtin_bit_cast(s16x8, o);
}
__device__ __forceinline__ s16x8 feat_mul(s16x8 k, s16x8 q) {
    u32x4 kk = __builtin_bit_cast(u32x4, k), qq = __builtin_bit_cast(u32x4, q);
    u32x4 o;
    #pragma unroll
    for (int p = 0; p < 4; ++p) {
        unsigned kp = kk[p], qp = qq[p];
        float klo = __builtin_bit_cast(float, kp << 16);
        float khi = __builtin_bit_cast(float, kp & 0xFFFF0000u);
        float qlo = __builtin_bit_cast(float, qp << 16);
        float qhi = __builtin_bit_cast(float, qp & 0xFFFF0000u);
        unsigned plo = __builtin_bit_cast(unsigned, qlo * klo);
        unsigned phi = __builtin_bit_cast(unsigned, qhi * khi);
        o[p] = (phi & 0xFFFF0000u) | (plo >> 16);
    }
    return __builtin_bit_cast(s16x8, o);
}

#define MFMA(a, b, c) __builtin_amdgcn_mfma_f32_16x16x32_bf16(a, b, c, 0, 0, 0)

// ---------- prep Wk -> [cb(8)*4+q][6 kt][128 cols][32 KP]
__global__ __launch_bounds__(256) void prep_wk(const float* __restrict__ W, u16* __restrict__ out) {
    int idx = blockIdx.x * 256 + threadIdx.x;   // 768*1024
    if (idx >= 768 * 1024) return;
    int k = idx >> 10, c = idx & 1023;
    int cb = c >> 7, ci = c & 127, kt = k >> 5, ki = k & 31;
    int q = kt / 6, kti = kt % 6;
    out[((size_t)(cb * 4 + q) * 6 + kti) * 4096 + ci * 32 + KP(ki)] = f2bf(W[idx]);
}

// ---------- prep W1 (all 512 rows incl. q-block) -> [ks=k>>5][256 cols][32 KP]
__global__ __launch_bounds__(256) void prep_w1(const float* __restrict__ W1, u16* __restrict__ out) {
    int idx = blockIdx.x * 256 + threadIdx.x;   // 512*256
    if (idx >= 512 * 256) return;
    int k = idx >> 8, c = idx & 255;
    out[(size_t)(k >> 5) * 8192 + c * 32 + KP(k & 31)] = f2bf(W1[idx]);
}

// ---------- prep W2' = (g1 rows-scaled W2) -> [ks][128 cols][32 KP]
__global__ __launch_bounds__(256) void prep_w2k(const float* __restrict__ W2,
                                                const float* __restrict__ g1, u16* __restrict__ w2t) {
    int idx = blockIdx.x * 256 + threadIdx.x;   // 256*128
    if (idx >= 32768) return;
    int k = idx >> 7, c = idx & 127;
    w2t[(size_t)(k >> 5) * 4096 + c * 32 + KP(k & 31)] = f2bf(g1[k] * W2[(size_t)k * 128 + c]);
}
// bias2[c] = b2[c] + sum_k ln1_b[k] * W2[k,c]
__global__ void prep_bias2(const float* __restrict__ W2, const float* __restrict__ lnb,
                           const float* __restrict__ b2, float* __restrict__ bias2) {
    int c = threadIdx.x;   // 128
    float s = b2[c];
    for (int k = 0; k < 256; ++k) s += lnb[k] * W2[k * 128 + c];
    bias2[c] = s;
}

// ---------- nf = LN(ent + role_emb[roles]) -> blocked bf16 tiles [(row>>7)*24+kt][128][32 KP]
__global__ __launch_bounds__(256) void nf_ln_kernel(
    const float* __restrict__ ent, const int* __restrict__ roles,
    const float* __restrict__ role_emb, const float* __restrict__ g,
    const float* __restrict__ bta, u16* __restrict__ nfb)
{
    int wave = threadIdx.x >> 6, lane = threadIdx.x & 63;
    int row = blockIdx.x * 4 + wave;
    const float* er = ent + (size_t)row * 768;
    const float* rr = role_emb + roles[row] * 768;
    float x[12]; float s = 0.f, s2 = 0.f;
    #pragma unroll
    for (int i = 0; i < 12; ++i) {
        x[i] = er[i * 64 + lane] + rr[i * 64 + lane];
        s += x[i]; s2 += x[i] * x[i];
    }
    s = wave_reduce_sum(s); s2 = wave_reduce_sum(s2);
    float mu = s * (1.f / 768.f);
    float var = s2 * (1.f / 768.f) - mu * mu;
    float rs = rsqrtf(var + 1e-5f);
    size_t rb = (size_t)(row >> 7) * 24;
    int rin = row & 127;
    #pragma unroll
    for (int i = 0; i < 12; ++i) {
        int k = i * 64 + lane;
        float v = (x[i] - mu) * rs * g[k] + bta[k];
        nfb[(rb + (k >> 5)) * 4096 + rin * 32 + KP(k & 31)] = f2bf(v);
    }
}

// ---------- q = gelu(q_emb @ Wq + bq) -> bf16 [64][32 chunks][32 KP]
__global__ __launch_bounds__(256) void q_kernel(
    const float* __restrict__ q_emb, const float* __restrict__ Wq,
    const float* __restrict__ bq, u16* __restrict__ qout)
{
    __shared__ float sq[768];
    int b = blockIdx.y;
    int col = blockIdx.x * 256 + threadIdx.x;
    for (int i = threadIdx.x; i < 768; i += 256) sq[i] = q_emb[b * 768 + i];
    __syncthreads();
    float acc = 0.f;
    #pragma unroll 4
    for (int k = 0; k < 768; ++k) acc = fmaf(sq[k], Wq[(size_t)k * 1024 + col], acc);
    qout[b * 1024 + (col >> 5) * 32 + KP(col & 31)] = f2bf(geluf(acc + bq[col]));
}

// ---------- kgemm: nf[8192x768] @ Wk[768x1024] + gelu -> kbuf [8192][32 chunks][32 KP]
// Weights-stationary: B 128-col x K-quarter in LDS (48KB, restaged 4x). No in-loop barriers.
__global__ __launch_bounds__(512) void kgemm(
    const u16* __restrict__ nfb, const u16* __restrict__ wkt,
    const float* __restrict__ bk, u16* __restrict__ kbuf)
{
    __shared__ __attribute__((aligned(16))) u16 bs[24576];
    const int tid = threadIdx.x, lane = tid & 63, wv = tid >> 6;
    const int lr = lane & 15, g = lane >> 4;
    const int nb = blockIdx.x;   // 0..7  (128-col slice)
    const int mb = blockIdx.y;   // 0..31 (256-row block)
    const int row0 = mb * 256 + wv * 32;
    float bv[8];
    #pragma unroll
    for (int j = 0; j < 8; ++j) bv[j] = bk[nb * 128 + j * 16 + lr];
    f32x4 acc[2][8];
    #pragma unroll
    for (int i = 0; i < 2; ++i)
        #pragma unroll
        for (int j = 0; j < 8; ++j) acc[i][j] = (f32x4){0.f, 0.f, 0.f, 0.f};
    s16x8 anx[2];
    auto loadA = [&](int t) {
        #pragma unroll
        for (int i = 0; i < 2; ++i) {
            int row = row0 + i * 16 + lr;
            anx[i] = *(const s16x8*)&nfb[((size_t)(row >> 7) * 24 + t) * 4096 + (row & 127) * 32 + g * 8];
        }
    };
    loadA(0);
    #pragma unroll 1
    for (int q = 0; q < 4; ++q) {
        if (q) __syncthreads();   // all reads of bs done
        for (int c = tid; c < 3072; c += 512)
            async_copy16(wkt + ((size_t)(nb * 4 + q)) * 24576 + c * 8, bs + c * 8);
        asm volatile("s_waitcnt vmcnt(0)" ::: "memory");
        __syncthreads();
        #pragma unroll
        for (int ti = 0; ti < 6; ++ti) {
            s16x8 a0 = anx[0], a1 = anx[1];
            if (ti < 5) loadA(q * 6 + ti + 1);
            else if (q < 3) loadA(q * 6 + 6);
            #pragma unroll
            for (int j = 0; j < 8; ++j) {
                s16x8 bf = *(const s16x8*)&bs[ti * 4096 + (j * 16 + lr) * 32 + g * 8];
                acc[0][j] = MFMA(a0, bf, acc[0][j]);
                acc[1][j] = MFMA(a1, bf, acc[1][j]);
            }
        }
    }
    // epilogue: gelu + KP-chunked store (layout h1h2 reads with single 16B loads)
    #pragma unroll
    for (int i = 0; i < 2; ++i)
        #pragma unroll
        for (int j = 0; j < 8; ++j) {
            int chunk = nb * 4 + (j >> 1);
            int pos = ((lr & 12) << 1) | ((j & 1) << 2) | (lr & 3);
            #pragma unroll
            for (int r = 0; r < 4; ++r) {
                int row = row0 + i * 16 + 4 * g + r;
                kbuf[(size_t)row * 1024 + chunk * 32 + pos] = f2bf(geluf(acc[i][j][r] + bv[j]));
            }
        }
}

// ---------- h1h2: interaction[65536x512]@W1 (+b1,gelu,LN) then @W2' (+bias2,gelu,LN,W3) -> scores
// rows' = (b*128+n)*8+h. Block = 128 rows', 8 waves x 16 rows. A entirely in registers
// (qf/kvr per lane, h = lr&7). W1 in LDS in two 128KB halves; W2' 64KB; ~6 barriers total.
__global__ __launch_bounds__(512) void h1h2(
    const u16* __restrict__ kbuf, const u16* __restrict__ qbuf,
    const u16* __restrict__ w1t, const u16* __restrict__ w2t,
    const float* __restrict__ b1v, const float* __restrict__ bias2,
    const float* __restrict__ g2v, const float* __restrict__ b2v,
    const float* __restrict__ W3, const float* __restrict__ b3,
    float* __restrict__ scores)
{
    __shared__ __attribute__((aligned(16))) u16 sm[66048];  // max(128KB W1-half, 64KB W2' + 8x4160 wbuf)
    const int tid = threadIdx.x, lane = tid & 63, wv = tid >> 6;
    const int lr = lane & 15, g = lane >> 4;
    const int blk = blockIdx.x;            // 0..511
    const int b = blk >> 3;
    const int row0 = blk * 128 + wv * 16;  // wave's 16 rows'
    const int h = lr & 7;
    const int krow = (row0 + lr) >> 3;

    // stage W1 first half (ks 0..7)
    for (int c = tid; c < 8192; c += 512)
        async_copy16(w1t + (size_t)c * 8, sm + c * 8);
    // per-lane constants (VMEM, drained by the same vmcnt(0))
    s16x8 qf[4], kvr[4];
    #pragma unroll
    for (int dt = 0; dt < 4; ++dt) {
        qf[dt]  = *(const s16x8*)&qbuf[(size_t)b * 1024 + (h * 4 + dt) * 32 + g * 8];
        kvr[dt] = *(const s16x8*)&kbuf[(size_t)krow * 1024 + (h * 4 + dt) * 32 + g * 8];
    }
    float b1c[16];
    #pragma unroll
    for (int j = 0; j < 16; ++j) b1c[j] = b1v[j * 16 + lr];
    float bc2[8], g2c[8], b2c[8], w3c[8];
    #pragma unroll
    for (int j = 0; j < 8; ++j) {
        int col = j * 16 + lr;
        bc2[j] = bias2[col]; g2c[j] = g2v[col]; b2c[j] = b2v[col]; w3c[j] = W3[col];
    }
    float b3v = b3[0];
    asm volatile("s_waitcnt vmcnt(0)" ::: "memory");
    __syncthreads();

    f32x4 acc[16];
    #pragma unroll
    for (int j = 0; j < 16; ++j) acc[j] = (f32x4){0.f, 0.f, 0.f, 0.f};
    // h1 first half: ks0..3 = q-block, ks4..7 = k-block
    #pragma unroll
    for (int ks = 0; ks < 8; ++ks) {
        s16x8 af = (ks < 4) ? qf[ks & 3] : kvr[ks & 3];
        #pragma unroll
        for (int j = 0; j < 16; ++j) {
            s16x8 bf = *(const s16x8*)&sm[ks * 8192 + (j * 16 + lr) * 32 + g * 8];
            acc[j] = MFMA(af, bf, acc[j]);
        }
    }
    __syncthreads();   // first-half reads done
    for (int c = tid; c < 8192; c += 512)
        async_copy16(w1t + (size_t)(65536 + c * 8), sm + c * 8);
    asm volatile("s_waitcnt vmcnt(0)" ::: "memory");
    __syncthreads();
    // h1 second half: ks8..11 = |q-k|, ks12..15 = q*k
    #pragma unroll
    for (int ks = 0; ks < 8; ++ks) {
        s16x8 af = (ks < 4) ? feat_abs(kvr[ks & 3], qf[ks & 3])
                            : feat_mul(kvr[ks & 3], qf[ks & 3]);
        #pragma unroll
        for (int j = 0; j < 16; ++j) {
            s16x8 bf = *(const s16x8*)&sm[ks * 8192 + (j * 16 + lr) * 32 + g * 8];
            acc[j] = MFMA(af, bf, acc[j]);
        }
    }
    __syncthreads();   // all W1 reads done; sm reusable
    // stage W2' (64KB) into sm[0..32768)
    for (int c = tid; c < 4096; c += 512)
        async_copy16(w2t + (size_t)c * 8, sm + c * 8);

    // h1 epilogue (registers): gelu(x + b1), LN over 256 cols per row
    float S[4] = {0.f, 0.f, 0.f, 0.f}, S2[4] = {0.f, 0.f, 0.f, 0.f};
    #pragma unroll
    for (int j = 0; j < 16; ++j) {
        f32x4 t = acc[j];
        #pragma unroll
        for (int r = 0; r < 4; ++r) {
            float v = geluf(t[r] + b1c[j]);
            t[r] = v; S[r] += v; S2[r] += v * v;
        }
        acc[j] = t;
    }
    #pragma unroll
    for (int r = 0; r < 4; ++r) {
        #pragma unroll
        for (int m = 1; m <= 8; m <<= 1) {
            S[r] += __shfl_xor(S[r], m, 64);
            S2[r] += __shfl_xor(S2[r], m, 64);
        }
    }
    float c0[4], c1[4];
    #pragma unroll
    for (int r = 0; r < 4; ++r) {
        float mu = S[r] * (1.f / 256.f);
        float var = S2[r] * (1.f / 256.f) - mu * mu;
        float rs = rsqrtf(var + 1e-5f);
        c1[r] = rs; c0[r] = -mu * rs;
    }
    // wave-private LDS transpose: y=(v-mu)*rs bf16 (g1 folded into W2')
    u16* wbuf = sm + 32768 + wv * 4160;   // [16 rows][260]
    #pragma unroll
    for (int j = 0; j < 16; ++j) {
        int pos = (j >> 1) * 32 + (((lr & 12) << 1) | ((j & 1) << 2) | (lr & 3));
        #pragma unroll
        for (int r = 0; r < 4; ++r)
            wbuf[(4 * g + r) * 260 + pos] = f2bf(fmaf(acc[j][r], c1[r], c0[r]));
    }
    asm volatile("s_waitcnt vmcnt(0)" ::: "memory");
    __syncthreads();   // W2' staged; wbuf writes drained by barrier's lgkm wait

    // h2: K=256, 8 steps, A from own wbuf, B from W2' LDS
    f32x4 acc2[8];
    #pragma unroll
    for (int j = 0; j < 8; ++j) acc2[j] = (f32x4){0.f, 0.f, 0.f, 0.f};
    #pragma unroll
    for (int ks = 0; ks < 8; ++ks) {
        s16x8 af = *(const s16x8*)&wbuf[lr * 260 + ks * 32 + g * 8];
        #pragma unroll
        for (int j = 0; j < 8; ++j) {
            s16x8 bf = *(const s16x8*)&sm[ks * 4096 + (j * 16 + lr) * 32 + g * 8];
            acc2[j] = MFMA(af, bf, acc2[j]);
        }
    }
    // epilogue: gelu(+bias2), LN(128), *g2+b2, dot W3 -> scores
    float T[4] = {0.f, 0.f, 0.f, 0.f}, T2[4] = {0.f, 0.f, 0.f, 0.f};
    #pragma unroll
    for (int j = 0; j < 8; ++j) {
        f32x4 t = acc2[j];
        #pragma unroll
        for (int r = 0; r < 4; ++r) {
            float v = geluf(t[r] + bc2[j]);
            t[r] = v; T[r] += v; T2[r] += v * v;
        }
        acc2[j] = t;
    }
    #pragma unroll
    for (int r = 0; r < 4; ++r) {
        #pragma unroll
        for (int m = 1; m <= 8; m <<= 1) {
            T[r] += __shfl_xor(T[r], m, 64);
            T2[r] += __shfl_xor(T2[r], m, 64);
        }
    }
    float d[4];
    #pragma unroll
    for (int r = 0; r < 4; ++r) {
        float mu = T[r] * (1.f / 128.f);
        float var = T2[r] * (1.f / 128.f) - mu * mu;
        float rs = rsqrtf(var + 1e-5f);
        float dd = 0.f;
        #pragma unroll
        for (int j = 0; j < 8; ++j) {
            float ln = (acc2[j][r] - mu) * rs * g2c[j] + b2c[j];
            dd = fmaf(ln, w3c[j], dd);
        }
        #pragma unroll
        for (int m = 1; m <= 8; m <<= 1) dd += __shfl_xor(dd, m, 64);
        d[r] = dd;
    }
    if (lr == 0) {
        #pragma unroll
        for (int r = 0; r < 4; ++r)
            scores[row0 + 4 * g + r] = d[r] + b3v;
    }
}

// ---------- out[b] = sigmoid( sum_{n,h} score*gate*mask / 8 ), rows' = (b*128+n)*8+h
__global__ __launch_bounds__(256) void final_kernel(
    const float* __restrict__ scores, const float* __restrict__ idfs,
    const float* __restrict__ mask, const float* __restrict__ gate_w,
    const float* __restrict__ gate_b, float* __restrict__ outp)
{
    int b = blockIdx.x, tid = threadIdx.x;
    float gw = gate_w[0], gb = gate_b[0];
    float acc = 0.f;
    for (int i = tid; i < 1024; i += 256) {
        int n = i >> 3;
        float lg = log1pf(idfs[b * 128 + n]);
        float gate = 1.f / (1.f + expf(-(lg * gw + gb)));
        acc += scores[b * 1024 + i] * gate * mask[b * 128 + n];
    }
    acc = wave_reduce_sum(acc);
    __shared__ float wsum[4];
    if ((tid & 63) == 0) wsum[tid >> 6] = acc;
    __syncthreads();
    if (tid == 0) {
        float t = wsum[0] + wsum[1] + wsum[2] + wsum[3];
        outp[b] = 1.f / (1.f + expf(-t * 0.125f));
    }
}

extern "C" void kernel_launch(void* const* d_in, const int* in_sizes, int n_in,
                              void* d_out, int out_size, void* d_ws, size_t ws_size,
                              hipStream_t stream) {
    const float* q_emb    = (const float*)d_in[0];
    const float* ent      = (const float*)d_in[1];
    const int*   roles    = (const int*)d_in[2];
    const float* idfs     = (const float*)d_in[3];
    const float* mask     = (const float*)d_in[4];
    const float* role_emb = (const float*)d_in[5];
    const float* ln_f_g   = (const float*)d_in[6];
    const float* ln_f_b   = (const float*)d_in[7];
    const float* Wq       = (const float*)d_in[8];
    const float* bq       = (const float*)d_in[9];
    const float* Wk       = (const float*)d_in[10];
    const float* bk       = (const float*)d_in[11];
    const float* W1       = (const float*)d_in[12];
    const float* b1       = (const float*)d_in[13];
    const float* ln1_g    = (const float*)d_in[14];
    const float* ln1_b    = (const float*)d_in[15];
    const float* W2       = (const float*)d_in[16];
    const float* b2       = (const float*)d_in[17];
    const float* ln2_g    = (const float*)d_in[18];
    const float* ln2_b    = (const float*)d_in[19];
    const float* W3       = (const float*)d_in[20];
    const float* b3       = (const float*)d_in[21];
    const float* gate_w   = (const float*)d_in[22];
    const float* gate_b   = (const float*)d_in[23];
    float* outp = (float*)d_out;

    // workspace layout (bytes), disjoint; peak ~31.7 MB
    char* ws = (char*)d_ws;
    u16*   nfb    = (u16*)(ws);                          // 12,582,912
    u16*   kbuf   = (u16*)(ws + (size_t)12582912);       // 16,777,216
    u16*   WkT    = (u16*)(ws + (size_t)29360128);       //  1,572,864
    u16*   W1T    = (u16*)(ws + (size_t)30932992);       //    262,144
    u16*   W2T    = (u16*)(ws + (size_t)31195136);       //     65,536
    u16*   qbuf   = (u16*)(ws + (size_t)31260672);       //    131,072
    float* bias2  = (float*)(ws + (size_t)31391744);     //        512
    float* scores = (float*)(ws + (size_t)31392256);     //    262,144

    prep_wk<<<3072, 256, 0, stream>>>(Wk, WkT);
    prep_w1<<<512, 256, 0, stream>>>(W1, W1T);
    prep_w2k<<<128, 256, 0, stream>>>(W2, ln1_g, W2T);
    prep_bias2<<<1, 128, 0, stream>>>(W2, ln1_b, b2, bias2);
    nf_ln_kernel<<<2048, 256, 0, stream>>>(ent, roles, role_emb, ln_f_g, ln_f_b, nfb);
    q_kernel<<<dim3(4, 64), 256, 0, stream>>>(q_emb, Wq, bq, qbuf);
    kgemm<<<dim3(8, 32), 512, 0, stream>>>(nfb, WkT, bk, kbuf);
    h1h2<<<512, 512, 0, stream>>>(kbuf, qbuf, W1T, W2T, b1, bias2,
                                  ln2_g, ln2_b, W3, b3, scores);
    final_kernel<<<64, 256, 0, stream>>>(scores, idfs, mask, gate_w, gate_b, outp);
}